// Round 1
// baseline (107.576 us; speedup 1.0000x reference)
//
#include <hip/hip_runtime.h>

// 3D Haar DWT, fixed problem size: x[N=4, C=4, D=64, H=256, W=256] f32.
// Outputs: 8 bands (LLL,LLH,LHL,LHH,HLL,HLH,HHL,HHH), each [4,4,32,128,128],
// concatenated flat in d_out. Band bit2=D-high, bit1=H-high, bit0=W-high.
//
// Each output voxel of every band is a signed sum of the same 2x2x2 input
// cube scaled by 2^-1.5. One thread handles TWO adjacent output columns:
// 4x float4 loads (rows (d0,h0),(d0,h1),(d1,h0),(d1,h1)), 8x float2 stores.

#define S3 0.35355339059327378f  // 2^-1.5

__global__ __launch_bounds__(256) void dwt3d_haar_kernel(
    const float* __restrict__ x, float* __restrict__ out) {
  // total threads = N*C * D/2 * H/2 * W/4 = 16 * 32 * 128 * 64 = 4,194,304
  const unsigned j = blockIdx.x * 256u + threadIdx.x;

  const unsigned wq = j & 63u;          // float4 index within input W row
  const unsigned hy = (j >> 6) & 127u;  // output h
  const unsigned dz = (j >> 13) & 31u;  // output d
  const unsigned nc = j >> 18;          // n*C + c, [0,16)

  // float offset of row (nc, d=2dz, h=2hy): (((nc*64 + 2dz)*256) + 2hy)*256
  const size_t row0 = ((size_t)nc * 64u + 2u * dz) * 256u + 2u * hy;
  const float* base = x + row0 * 256u;

  // rows: A=(d0,h0) B=(d0,h1) C=(d1,h0) D=(d1,h1); h+1 -> +256 floats,
  // d+1 -> +65536 floats
  const float4 A = ((const float4*)(base))[wq];
  const float4 B = ((const float4*)(base + 256))[wq];
  const float4 C = ((const float4*)(base + 65536))[wq];
  const float4 D = ((const float4*)(base + 65536 + 256))[wq];

  // W-axis butterflies (two output columns k=0,1 per row)
  float awl0 = A.x + A.y, awh0 = A.x - A.y, awl1 = A.z + A.w, awh1 = A.z - A.w;
  float bwl0 = B.x + B.y, bwh0 = B.x - B.y, bwl1 = B.z + B.w, bwh1 = B.z - B.w;
  float cwl0 = C.x + C.y, cwh0 = C.x - C.y, cwl1 = C.z + C.w, cwh1 = C.z - C.w;
  float dwl0 = D.x + D.y, dwh0 = D.x - D.y, dwl1 = D.z + D.w, dwh1 = D.z - D.w;

  // H-axis: combine (d0,h0)+(d0,h1) and (d1,h0)+(d1,h1)
  // naming: d{0,1}_{hFilter}{wFilter}{col}
  float d0_ll0 = awl0 + bwl0, d0_hl0 = awl0 - bwl0;
  float d0_lh0 = awh0 + bwh0, d0_hh0 = awh0 - bwh0;
  float d0_ll1 = awl1 + bwl1, d0_hl1 = awl1 - bwl1;
  float d0_lh1 = awh1 + bwh1, d0_hh1 = awh1 - bwh1;
  float d1_ll0 = cwl0 + dwl0, d1_hl0 = cwl0 - dwl0;
  float d1_lh0 = cwh0 + dwh0, d1_hh0 = cwh0 - dwh0;
  float d1_ll1 = cwl1 + dwl1, d1_hl1 = cwl1 - dwl1;
  float d1_lh1 = cwh1 + dwh1, d1_hh1 = cwh1 - dwh1;

  // D-axis + scale; band = (Dhigh<<2)|(Hhigh<<1)|(Whigh)
  float2 r0 = make_float2(S3 * (d0_ll0 + d1_ll0), S3 * (d0_ll1 + d1_ll1)); // LLL
  float2 r1 = make_float2(S3 * (d0_lh0 + d1_lh0), S3 * (d0_lh1 + d1_lh1)); // LLH
  float2 r2 = make_float2(S3 * (d0_hl0 + d1_hl0), S3 * (d0_hl1 + d1_hl1)); // LHL
  float2 r3 = make_float2(S3 * (d0_hh0 + d1_hh0), S3 * (d0_hh1 + d1_hh1)); // LHH
  float2 r4 = make_float2(S3 * (d0_ll0 - d1_ll0), S3 * (d0_ll1 - d1_ll1)); // HLL
  float2 r5 = make_float2(S3 * (d0_lh0 - d1_lh0), S3 * (d0_lh1 - d1_lh1)); // HLH
  float2 r6 = make_float2(S3 * (d0_hl0 - d1_hl0), S3 * (d0_hl1 - d1_hl1)); // HHL
  float2 r7 = make_float2(S3 * (d0_hh0 - d1_hh0), S3 * (d0_hh1 - d1_hh1)); // HHH

  // per-band element count = 8,388,608 floats; float2 index is exactly j
  const size_t BAND = 8388608;
  ((float2*)(out + 0 * BAND))[j] = r0;
  ((float2*)(out + 1 * BAND))[j] = r1;
  ((float2*)(out + 2 * BAND))[j] = r2;
  ((float2*)(out + 3 * BAND))[j] = r3;
  ((float2*)(out + 4 * BAND))[j] = r4;
  ((float2*)(out + 5 * BAND))[j] = r5;
  ((float2*)(out + 6 * BAND))[j] = r6;
  ((float2*)(out + 7 * BAND))[j] = r7;
}

extern "C" void kernel_launch(void* const* d_in, const int* in_sizes, int n_in,
                              void* d_out, int out_size, void* d_ws, size_t ws_size,
                              hipStream_t stream) {
  const float* x = (const float*)d_in[0];
  float* out = (float*)d_out;
  // 4,194,304 threads / 256 = 16384 blocks
  dwt3d_haar_kernel<<<16384, 256, 0, stream>>>(x, out);
}